// Round 1
// baseline (1315.046 us; speedup 1.0000x reference)
//
#include <hip/hip_runtime.h>
#include <hip/hip_bf16.h>
#include <math.h>

#define BATCH 4
#define C 128
#define H 88
#define W 88
#define HW 7744
#define HALF 44
#define CH2 1024
#define HIDDEN 512
#define TILE 32          // pixels per block
#define BLOCKS_PER_B 242 // 7744/32
#define NBLK (BATCH * BLOCKS_PER_B)

// bilinear 2x upsample taps (jax half-pixel, clamped+renormalized == clamp both taps)
__device__ __forceinline__ void up_taps(int i, int& j0, int& j1, float& w0, float& w1) {
    float f = 0.5f * i - 0.25f;
    int i0 = (int)floorf(f);
    float fr = f - (float)i0;
    j0 = max(i0, 0);
    j1 = min(i0 + 1, HALF - 1);
    w0 = 1.f - fr;
    w1 = fr;
}

// ---------------- Kernel 1: LN1 + upsample + QKV + per-pixel attention + scatter add ----------------
__global__ __launch_bounds__(256) void k_attn(
    const float* __restrict__ x, const float* __restrict__ mask,
    const float* __restrict__ edge, const float* __restrict__ ln1w,
    const float* __restrict__ ln1b, const float* __restrict__ Wq,
    const float* __restrict__ Wk, const float* __restrict__ Wv,
    float* __restrict__ x1)
{
    __shared__ float eT[C][TILE];
    __shared__ float xT[C][TILE];  // x -> xnm in place
    __shared__ float qT[C][TILE];
    __shared__ float kT[C][TILE];
    __shared__ float vT[C][TILE];

    const int tid = threadIdx.x;
    const int s = tid >> 5;   // 0..7
    const int px = tid & 31;
    const int blk = blockIdx.x;
    const int b = blk / BLOCKS_PER_B;
    const int hw0 = (blk % BLOCKS_PER_B) * TILE;
    const int hw = hw0 + px;
    const int hi = hw / W, wi = hw % W;

    int y0, y1, x0, x1c; float wy0, wy1, wx0, wx1;
    up_taps(hi, y0, y1, wy0, wy1);
    up_taps(wi, x0, x1c, wx0, wx1);

    const float* mb = mask + (size_t)b * HALF * HALF;
    const float mval = wy0 * (wx0 * mb[y0 * HALF + x0] + wx1 * mb[y0 * HALF + x1c])
                     + wy1 * (wx0 * mb[y1 * HALF + x0] + wx1 * mb[y1 * HALF + x1c]);

    const float* xb = x + (size_t)b * C * HW;
    const float* eb = edge + (size_t)b * C * HALF * HALF;
    for (int c = s; c < C; c += 8) {
        xT[c][px] = xb[c * HW + hw];
        const float* ec = eb + c * HALF * HALF;
        eT[c][px] = wy0 * (wx0 * ec[y0 * HALF + x0] + wx1 * ec[y0 * HALF + x1c])
                  + wy1 * (wx0 * ec[y1 * HALF + x0] + wx1 * ec[y1 * HALF + x1c]);
    }
    __syncthreads();

    // LN over channels (each of the 8 threads per pixel computes redundantly)
    float sum = 0.f, sq = 0.f;
    for (int c = 0; c < C; ++c) { float t = xT[c][px]; sum += t; sq += t * t; }
    const float mu = sum * (1.f / C);
    const float rstd = rsqrtf(sq * (1.f / C) - mu * mu + 1e-5f);
    __syncthreads();
    for (int c = s; c < C; c += 8)
        xT[c][px] = ((xT[c][px] - mu) * rstd * ln1w[c] + ln1b[c]) * mval;
    __syncthreads();

    // QKV: 16 output channels per thread, blocked 4-wide, float4 weights
    for (int g = 0; g < 4; ++g) {
        float aq[4] = {0,0,0,0}, ak[4] = {0,0,0,0}, av[4] = {0,0,0,0};
        const int cobase = s + 32 * g;
        #pragma unroll 4
        for (int c4 = 0; c4 < 32; ++c4) {
            const int c = 4 * c4;
            float ev0 = eT[c][px], ev1 = eT[c+1][px], ev2 = eT[c+2][px], ev3 = eT[c+3][px];
            float xv0 = xT[c][px], xv1 = xT[c+1][px], xv2 = xT[c+2][px], xv3 = xT[c+3][px];
            #pragma unroll
            for (int q = 0; q < 4; ++q) {
                const int co = cobase + 8 * q;
                float4 fq = *(const float4*)(Wq + co * C + c);
                float4 fk = *(const float4*)(Wk + co * C + c);
                float4 fv = *(const float4*)(Wv + co * C + c);
                aq[q] += fq.x*ev0 + fq.y*ev1 + fq.z*ev2 + fq.w*ev3;
                ak[q] += fk.x*xv0 + fk.y*xv1 + fk.z*xv2 + fk.w*xv3;
                av[q] += fv.x*xv0 + fv.y*xv1 + fv.z*xv2 + fv.w*xv3;
            }
        }
        #pragma unroll
        for (int q = 0; q < 4; ++q) {
            const int co = cobase + 8 * q;
            qT[co][px] = aq[q]; kT[co][px] = ak[q]; vT[co][px] = av[q];
        }
    }
    __syncthreads();

    // attention: thread owns rows j = s + 8*rr (full softmax axis in registers)
    const int r_ = hi >> 2, col = wi >> 2, n = (hi & 3) * 4 + (wi & 3);
    const float scale = 0.125f; // 64^-0.5
    const size_t bbase = (size_t)b * C * HW;
    const int wbase = r_ * 22 + col;
    for (int rr = 0; rr < 8; ++rr) {
        const int j = s + 8 * rr;
        const float q1 = qT[j][px], q2 = qT[64 + j][px];
        float dv[64];
        float mx = -1e30f;
        #pragma unroll
        for (int kk = 0; kk < 64; ++kk) {
            float d = (q1 * kT[kk][px] + q2 * kT[64 + kk][px]) * scale;
            dv[kk] = d; mx = fmaxf(mx, d);
        }
        float ssum = 0.f;
        #pragma unroll
        for (int kk = 0; kk < 64; ++kk) { float e = __expf(dv[kk] - mx); dv[kk] = e; ssum += e; }
        const float inv = 1.f / ssum;
        float o1 = 0.f, o2 = 0.f;
        #pragma unroll
        for (int kk = 0; kk < 64; ++kk) { o1 += dv[kk] * vT[kk][px]; o2 += dv[kk] * vT[64 + kk][px]; }
        o1 *= inv; o2 *= inv;
        // scrambled destination: f = (n*128 + cj)*484 + r*22 + col,  cj = h*64 + j
        const int f1 = (n * C + j) * 484 + wbase;
        const int f2 = (n * C + 64 + j) * 484 + wbase;
        x1[bbase + f1] = x[bbase + f1] + o1;
        x1[bbase + f2] = x[bbase + f2] + o2;
    }
}

// ---------------- Kernel 2: LN2 + w_in GEMM -> u (bf16) ----------------
__global__ __launch_bounds__(256) void k_ffn1(
    const float* __restrict__ x1, const float* __restrict__ ln2w,
    const float* __restrict__ ln2b, const float* __restrict__ w_in,
    __hip_bfloat16* __restrict__ u)
{
    __shared__ float xT[C][TILE];
    const int tid = threadIdx.x;
    const int s = tid >> 5;
    const int px = tid & 31;
    const int blk = blockIdx.x;
    const int b = blk / BLOCKS_PER_B;
    const int hw0 = (blk % BLOCKS_PER_B) * TILE;
    const int hw = hw0 + px;

    const float* xb = x1 + (size_t)b * C * HW;
    for (int c = s; c < C; c += 8) xT[c][px] = xb[c * HW + hw];
    __syncthreads();
    float sum = 0.f, sq = 0.f;
    for (int c = 0; c < C; ++c) { float t = xT[c][px]; sum += t; sq += t * t; }
    const float mu = sum * (1.f / C);
    const float rstd = rsqrtf(sq * (1.f / C) - mu * mu + 1e-5f);
    __syncthreads();
    for (int c = s; c < C; c += 8)
        xT[c][px] = (xT[c][px] - mu) * rstd * ln2w[c] + ln2b[c];
    __syncthreads();

    __hip_bfloat16* ub = u + (size_t)b * CH2 * HW;
    // 128 outputs per thread, blocked 8-wide
    for (int g = 0; g < 16; ++g) {
        float acc[8] = {0,0,0,0,0,0,0,0};
        const int cobase = s + 64 * g;
        #pragma unroll 2
        for (int c4 = 0; c4 < 32; ++c4) {
            const int c = 4 * c4;
            float xv0 = xT[c][px], xv1 = xT[c+1][px], xv2 = xT[c+2][px], xv3 = xT[c+3][px];
            #pragma unroll
            for (int q = 0; q < 8; ++q) {
                float4 f = *(const float4*)(w_in + (cobase + 8 * q) * C + c);
                acc[q] += f.x*xv0 + f.y*xv1 + f.z*xv2 + f.w*xv3;
            }
        }
        #pragma unroll
        for (int q = 0; q < 8; ++q)
            ub[(size_t)(cobase + 8 * q) * HW + hw] = __float2bfloat16(acc[q]);
    }
}

// ---------------- Kernel 3: dwconv3x3 + gelu-gate + w_out GEMM + residual ----------------
__global__ __launch_bounds__(256) void k_ffn2(
    const float* __restrict__ x1, const __hip_bfloat16* __restrict__ u,
    const float* __restrict__ w_dw, const float* __restrict__ w_out,
    float* __restrict__ out)
{
    __shared__ float gT[HIDDEN][TILE]; // 64KB
    const int tid = threadIdx.x;
    const int s = tid >> 5;
    const int px = tid & 31;
    const int blk = blockIdx.x;
    const int b = blk / BLOCKS_PER_B;
    const int hw0 = (blk % BLOCKS_PER_B) * TILE;
    const int hw = hw0 + px;
    const int hi = hw / W, wi = hw % W;

    const __hip_bfloat16* ub = u + (size_t)b * CH2 * HW;
    for (int t = 0; t < 64; ++t) {
        const int co = s + 8 * t; // 0..511
        float t1 = 0.f, t2 = 0.f;
        const float* wd1 = w_dw + co * 9;
        const float* wd2 = w_dw + (co + HIDDEN) * 9;
        const __hip_bfloat16* u1 = ub + (size_t)co * HW;
        const __hip_bfloat16* u2 = ub + (size_t)(co + HIDDEN) * HW;
        #pragma unroll
        for (int ky = 0; ky < 3; ++ky) {
            const int y = hi + ky - 1;
            if ((unsigned)y >= H) continue;
            #pragma unroll
            for (int kx = 0; kx < 3; ++kx) {
                const int xc = wi + kx - 1;
                if ((unsigned)xc >= W) continue;
                const int off = y * W + xc;
                t1 += wd1[ky * 3 + kx] * __bfloat162float(u1[off]);
                t2 += wd2[ky * 3 + kx] * __bfloat162float(u2[off]);
            }
        }
        const float g = 0.5f * t1 * (1.f + erff(t1 * 0.70710678118654752f));
        gT[co][px] = g * t2;
    }
    __syncthreads();

    const float* x1b = x1 + (size_t)b * C * HW;
    float* ob = out + (size_t)b * C * HW;
    for (int g = 0; g < 4; ++g) {
        float acc[4] = {0,0,0,0};
        const int cbase = s + 32 * g;
        #pragma unroll 4
        for (int co4 = 0; co4 < 128; ++co4) {
            const int co = 4 * co4;
            float g0 = gT[co][px], g1 = gT[co+1][px], g2 = gT[co+2][px], g3 = gT[co+3][px];
            #pragma unroll
            for (int q = 0; q < 4; ++q) {
                float4 f = *(const float4*)(w_out + (cbase + 8 * q) * HIDDEN + co);
                acc[q] += f.x*g0 + f.y*g1 + f.z*g2 + f.w*g3;
            }
        }
        #pragma unroll
        for (int q = 0; q < 4; ++q) {
            const int c = cbase + 8 * q;
            ob[c * HW + hw] = x1b[c * HW + hw] + acc[q];
        }
    }
}

extern "C" void kernel_launch(void* const* d_in, const int* in_sizes, int n_in,
                              void* d_out, int out_size, void* d_ws, size_t ws_size,
                              hipStream_t stream) {
    (void)in_sizes; (void)n_in; (void)out_size; (void)ws_size;
    const float* x     = (const float*)d_in[0];
    const float* mask  = (const float*)d_in[1];
    const float* edge  = (const float*)d_in[2];
    const float* ln1w  = (const float*)d_in[3];
    const float* ln1b  = (const float*)d_in[4];
    const float* Wq    = (const float*)d_in[5];
    const float* Wk    = (const float*)d_in[6];
    const float* Wv    = (const float*)d_in[7];
    const float* ln2w  = (const float*)d_in[8];
    const float* ln2b  = (const float*)d_in[9];
    const float* w_in  = (const float*)d_in[10];
    const float* w_dw  = (const float*)d_in[11];
    const float* w_out = (const float*)d_in[12];
    float* out = (float*)d_out;

    char* ws = (char*)d_ws;
    float* x1 = (float*)ws;                                   // 15,859,712 B
    __hip_bfloat16* u = (__hip_bfloat16*)(ws + (size_t)BATCH * C * HW * 4); // 63,438,848 B

    k_attn<<<NBLK, 256, 0, stream>>>(x, mask, edge, ln1w, ln1b, Wq, Wk, Wv, x1);
    k_ffn1<<<NBLK, 256, 0, stream>>>(x1, ln2w, ln2b, w_in, u);
    k_ffn2<<<NBLK, 256, 0, stream>>>(x1, u, w_dw, w_out, out);
}

// Round 2
// 544.032 us; speedup vs baseline: 2.4172x; 2.4172x over previous
//
#include <hip/hip_runtime.h>
#include <hip/hip_bf16.h>
#include <math.h>

#define BATCH 4
#define C 128
#define H 88
#define W 88
#define HW 7744
#define NPIX 30976   // BATCH*HW
#define HALF 44
#define HID 512

typedef __attribute__((ext_vector_type(8))) short bfrag;   // 8 x bf16 (4 VGPR)
typedef __attribute__((ext_vector_type(4))) float f32x4;

__device__ __forceinline__ short f2bf(float f) {
    union { __hip_bfloat16 b; unsigned short u; } cv;
    cv.b = __float2bfloat16(f);
    return (short)cv.u;
}
__device__ __forceinline__ float bf2f(short s) {
    union { unsigned int u; float f; } cv;
    cv.u = ((unsigned int)(unsigned short)s) << 16;
    return cv.f;
}

// bilinear 2x upsample taps (jax half-pixel, clamped)
__device__ __forceinline__ void up_taps(int i, int& j0, int& j1, float& w0, float& w1) {
    float f = 0.5f * i - 0.25f;
    int i0 = (int)floorf(f);
    float fr = f - (float)i0;
    j0 = max(i0, 0);
    j1 = min(i0 + 1, HALF - 1);
    w0 = 1.f - fr;
    w1 = fr;
}

// ---------------- K1: LN1+mask -> xnm (bf16 pixel-major); edge upsample -> e ----------------
__global__ __launch_bounds__(256) void k_pre(
    const float* __restrict__ x, const float* __restrict__ mask,
    const float* __restrict__ edge, const float* __restrict__ ln1w,
    const float* __restrict__ ln1b,
    __hip_bfloat16* __restrict__ xnm, __hip_bfloat16* __restrict__ eo)
{
    __shared__ float xT[C][32];
    __shared__ float eT[C][32];
    const int tid = threadIdx.x, s = tid >> 5, px = tid & 31;
    const int blk = blockIdx.x, b = blk / 242, hw0 = (blk % 242) * 32;
    const int hw = hw0 + px, hi = hw / W, wi = hw % W;

    int y0, y1, x0, x1c; float wy0, wy1, wx0, wx1;
    up_taps(hi, y0, y1, wy0, wy1);
    up_taps(wi, x0, x1c, wx0, wx1);

    const float* mb = mask + (size_t)b * HALF * HALF;
    const float mval = wy0 * (wx0 * mb[y0 * HALF + x0] + wx1 * mb[y0 * HALF + x1c])
                     + wy1 * (wx0 * mb[y1 * HALF + x0] + wx1 * mb[y1 * HALF + x1c]);

    const float* xb = x + (size_t)b * C * HW;
    const float* eb = edge + (size_t)b * C * HALF * HALF;
    for (int c = s; c < C; c += 8) {
        xT[c][px] = xb[c * HW + hw];
        const float* ec = eb + c * HALF * HALF;
        eT[c][px] = wy0 * (wx0 * ec[y0 * HALF + x0] + wx1 * ec[y0 * HALF + x1c])
                  + wy1 * (wx0 * ec[y1 * HALF + x0] + wx1 * ec[y1 * HALF + x1c]);
    }
    __syncthreads();
    float sum = 0.f, sq = 0.f;
    for (int c = 0; c < C; ++c) { float t = xT[c][px]; sum += t; sq += t * t; }
    const float mu = sum * (1.f / C);
    const float rstd = rsqrtf(sq * (1.f / C) - mu * mu + 1e-5f);
    __syncthreads();
    for (int c = s; c < C; c += 8)
        xT[c][px] = ((xT[c][px] - mu) * rstd * ln1w[c] + ln1b[c]) * mval;
    __syncthreads();

    const size_t gp = (size_t)b * HW + hw;
    const int cs = s * 16;
    bfrag r0, r1;
    #pragma unroll
    for (int i = 0; i < 8; ++i) { r0[i] = f2bf(xT[cs + i][px]); r1[i] = f2bf(xT[cs + 8 + i][px]); }
    *(bfrag*)((short*)xnm + gp * C + cs) = r0;
    *(bfrag*)((short*)xnm + gp * C + cs + 8) = r1;
    #pragma unroll
    for (int i = 0; i < 8; ++i) { r0[i] = f2bf(eT[cs + i][px]); r1[i] = f2bf(eT[cs + 8 + i][px]); }
    *(bfrag*)((short*)eo + gp * C + cs) = r0;
    *(bfrag*)((short*)eo + gp * C + cs + 8) = r1;
}

// ---------------- GEMM K=128: Out[p][lc] = sum_k A[p][k] * Wf[gc][k]  (MFMA bf16) ----------------
__global__ __launch_bounds__(512, 2) void k_gemm128(
    const __hip_bfloat16* __restrict__ A,   // [NPIX][128] bf16
    const float* __restrict__ Wf,           // [*][128] fp32
    __hip_bfloat16* __restrict__ Out,       // [NPIX][outStride] bf16
    int outStride, int passMode)
{
    const int lane = threadIdx.x & 63, wv = threadIdx.x >> 6;
    const int wm = wv & 3, wn = wv >> 2;
    const int px0 = blockIdx.x * 256 + wm * 64;
    const int lc0 = blockIdx.y * 128 + wn * 64;
    int gc0 = lc0;
    if (passMode >= 0)
        gc0 = (lc0 < 256) ? passMode * 256 + lc0 : 512 + passMode * 256 + (lc0 - 256);
    const int lr = lane & 15, lg = lane >> 4;

    // preload + cvt 16 B-frags (weights) into registers
    bfrag Bf[4][4];
    #pragma unroll
    for (int nj = 0; nj < 4; ++nj) {
        const float* wr = Wf + (size_t)(gc0 + nj * 16 + lr) * 128;
        #pragma unroll
        for (int ks = 0; ks < 4; ++ks) {
            const float4 f0 = *(const float4*)(wr + ks * 32 + lg * 8);
            const float4 f1 = *(const float4*)(wr + ks * 32 + lg * 8 + 4);
            bfrag t;
            t[0] = f2bf(f0.x); t[1] = f2bf(f0.y); t[2] = f2bf(f0.z); t[3] = f2bf(f0.w);
            t[4] = f2bf(f1.x); t[5] = f2bf(f1.y); t[6] = f2bf(f1.z); t[7] = f2bf(f1.w);
            Bf[nj][ks] = t;
        }
    }
    f32x4 acc[4][4];
    #pragma unroll
    for (int i = 0; i < 4; ++i)
        #pragma unroll
        for (int j = 0; j < 4; ++j)
            #pragma unroll
            for (int r = 0; r < 4; ++r) acc[i][j][r] = 0.f;

    const short* As = (const short*)A;
    #pragma unroll
    for (int ks = 0; ks < 4; ++ks) {
        bfrag a[4];
        #pragma unroll
        for (int mi = 0; mi < 4; ++mi)
            a[mi] = *(const bfrag*)(As + (size_t)(px0 + mi * 16 + lr) * 128 + ks * 32 + lg * 8);
        #pragma unroll
        for (int mi = 0; mi < 4; ++mi)
            #pragma unroll
            for (int nj = 0; nj < 4; ++nj)
                acc[mi][nj] = __builtin_amdgcn_mfma_f32_16x16x32_bf16(a[mi], Bf[nj][ks], acc[mi][nj], 0, 0, 0);
    }
    short* Os = (short*)Out;
    #pragma unroll
    for (int mi = 0; mi < 4; ++mi)
        #pragma unroll
        for (int nj = 0; nj < 4; ++nj)
            #pragma unroll
            for (int r = 0; r < 4; ++r) {
                const int p = px0 + mi * 16 + lg * 4 + r;
                const int c = lc0 + nj * 16 + lr;
                Os[(size_t)p * outStride + c] = f2bf(acc[mi][nj][r]);
            }
}

// ---------------- Attention: per-pixel 64x64 softmax; x1 = x + out (bf16, scattered) ----------------
__global__ __launch_bounds__(256) void k_attn2(
    const __hip_bfloat16* __restrict__ Q, const __hip_bfloat16* __restrict__ Kb,
    const __hip_bfloat16* __restrict__ Vb, const float* __restrict__ x,
    __hip_bfloat16* __restrict__ x1)
{
    __shared__ float qT[C][32], kT[C][32], vT[C][32];
    const int tid = threadIdx.x, s = tid >> 5, px = tid & 31;
    const int blk = blockIdx.x, b = blk / 242, hw0 = (blk % 242) * 32;
    const int hw = hw0 + px, hi = hw / W, wi = hw % W;
    const size_t gp = (size_t)b * HW + hw;
    const int cs = s * 16;
    {
        const short* qs = (const short*)Q + gp * C + cs;
        const short* ks = (const short*)Kb + gp * C + cs;
        const short* vs = (const short*)Vb + gp * C + cs;
        bfrag a0 = *(const bfrag*)qs, a1 = *(const bfrag*)(qs + 8);
        bfrag b0 = *(const bfrag*)ks, b1 = *(const bfrag*)(ks + 8);
        bfrag c0 = *(const bfrag*)vs, c1 = *(const bfrag*)(vs + 8);
        #pragma unroll
        for (int i = 0; i < 8; ++i) {
            qT[cs + i][px] = bf2f(a0[i]); qT[cs + 8 + i][px] = bf2f(a1[i]);
            kT[cs + i][px] = bf2f(b0[i]); kT[cs + 8 + i][px] = bf2f(b1[i]);
            vT[cs + i][px] = bf2f(c0[i]); vT[cs + 8 + i][px] = bf2f(c1[i]);
        }
    }
    __syncthreads();

    const int r_ = hi >> 2, col = wi >> 2, n = (hi & 3) * 4 + (wi & 3);
    const size_t bbase = (size_t)b * C * HW;
    const int wbase = r_ * 22 + col;
    for (int rr = 0; rr < 8; ++rr) {
        const int j = s + 8 * rr;
        const float q1v = qT[j][px], q2v = qT[64 + j][px];
        float dv[64];
        float mx = -1e30f;
        #pragma unroll
        for (int kk = 0; kk < 64; ++kk) {
            float d = (q1v * kT[kk][px] + q2v * kT[64 + kk][px]) * 0.125f;
            dv[kk] = d; mx = fmaxf(mx, d);
        }
        float ssum = 0.f;
        #pragma unroll
        for (int kk = 0; kk < 64; ++kk) { float e = __expf(dv[kk] - mx); dv[kk] = e; ssum += e; }
        const float inv = 1.f / ssum;
        float o1 = 0.f, o2 = 0.f;
        #pragma unroll
        for (int kk = 0; kk < 64; ++kk) { o1 += dv[kk] * vT[kk][px]; o2 += dv[kk] * vT[64 + kk][px]; }
        o1 *= inv; o2 *= inv;
        const int f1 = (n * C + j) * 484 + wbase;
        const int f2 = (n * C + 64 + j) * 484 + wbase;
        x1[bbase + f1] = __float2bfloat16(x[bbase + f1] + o1);
        x1[bbase + f2] = __float2bfloat16(x[bbase + f2] + o2);
    }
}

// ---------------- LN2: x1(bf16, ch-major) -> xn2 (bf16, pixel-major) ----------------
__global__ __launch_bounds__(256) void k_ln2(
    const __hip_bfloat16* __restrict__ x1, const float* __restrict__ ln2w,
    const float* __restrict__ ln2b, __hip_bfloat16* __restrict__ xn2)
{
    __shared__ float xT[C][32];
    const int tid = threadIdx.x, s = tid >> 5, px = tid & 31;
    const int blk = blockIdx.x, b = blk / 242, hw0 = (blk % 242) * 32;
    const int hw = hw0 + px;
    const __hip_bfloat16* xb = x1 + (size_t)b * C * HW;
    for (int c = s; c < C; c += 8) xT[c][px] = __bfloat162float(xb[c * HW + hw]);
    __syncthreads();
    float sum = 0.f, sq = 0.f;
    for (int c = 0; c < C; ++c) { float t = xT[c][px]; sum += t; sq += t * t; }
    const float mu = sum * (1.f / C);
    const float rstd = rsqrtf(sq * (1.f / C) - mu * mu + 1e-5f);
    __syncthreads();
    for (int c = s; c < C; c += 8)
        xT[c][px] = (xT[c][px] - mu) * rstd * ln2w[c] + ln2b[c];
    __syncthreads();
    const size_t gp = (size_t)b * HW + hw;
    const int cs = s * 16;
    bfrag r0, r1;
    #pragma unroll
    for (int i = 0; i < 8; ++i) { r0[i] = f2bf(xT[cs + i][px]); r1[i] = f2bf(xT[cs + 8 + i][px]); }
    *(bfrag*)((short*)xn2 + gp * C + cs) = r0;
    *(bfrag*)((short*)xn2 + gp * C + cs + 8) = r1;
}

// ---------------- depthwise 3x3 + gelu gate (one channel-half pass) ----------------
__global__ __launch_bounds__(256) void k_dw(
    const __hip_bfloat16* __restrict__ U,   // [NPIX][512] local (t1: 0..255, t2: 256..511)
    const float* __restrict__ wdw,          // [1024][9]
    __hip_bfloat16* __restrict__ Gout,      // [NPIX][512] global hidden cols
    int pass)
{
    const int cl = threadIdx.x;             // 0..255
    const int gr = blockIdx.x;              // 0..351 (b*88+hi)
    const int b = gr / H, hi = gr % H;
    const int gc1 = pass * 256 + cl, gc2 = 512 + gc1;
    float w1[9], w2[9];
    #pragma unroll
    for (int t = 0; t < 9; ++t) { w1[t] = wdw[gc1 * 9 + t]; w2[t] = wdw[gc2 * 9 + t]; }
    const size_t rowbase = (size_t)b * HW + (size_t)hi * W;
    for (int wi = 0; wi < W; ++wi) {
        float t1 = 0.f, t2 = 0.f;
        #pragma unroll
        for (int ky = 0; ky < 3; ++ky) {
            const int y = hi + ky - 1;
            if ((unsigned)y >= H) continue;
            #pragma unroll
            for (int kx = 0; kx < 3; ++kx) {
                const int xx = wi + kx - 1;
                if ((unsigned)xx >= W) continue;
                const size_t pn = (size_t)b * HW + (size_t)y * W + xx;
                t1 += w1[ky * 3 + kx] * __bfloat162float(U[pn * 512 + cl]);
                t2 += w2[ky * 3 + kx] * __bfloat162float(U[pn * 512 + 256 + cl]);
            }
        }
        const float gl = 0.5f * t1 * (1.f + erff(t1 * 0.70710678118654752f));
        Gout[(rowbase + wi) * 512 + pass * 256 + cl] = __float2bfloat16(gl * t2);
    }
}

// ---------------- small cvt: w_out fp32 -> bf16 ----------------
__global__ __launch_bounds__(256) void k_cvt(const float* __restrict__ src,
                                             __hip_bfloat16* __restrict__ dst, int n) {
    int i = blockIdx.x * 256 + threadIdx.x;
    if (i < n) dst[i] = __float2bfloat16(src[i]);
}

// ---------------- GEMM K=512 + residual: out = x1 + w_out @ g ----------------
__global__ __launch_bounds__(512, 2) void k_gemm512(
    const __hip_bfloat16* __restrict__ G,   // [NPIX][512]
    const __hip_bfloat16* __restrict__ Wob, // [128][512] bf16
    const __hip_bfloat16* __restrict__ X1,  // [B][C][HW] bf16
    float* __restrict__ Outp)               // [B][C][HW] f32
{
    const int lane = threadIdx.x & 63, wv = threadIdx.x >> 6;
    const int wm = wv & 3, wn = wv >> 2;    // wn 0..1
    const int px0 = blockIdx.x * 256 + wm * 64;
    const int c0 = blockIdx.y * 64 + wn * 32;
    const int lr = lane & 15, lg = lane >> 4;
    const short* Ws = (const short*)Wob;
    bfrag Bf[2][16];
    #pragma unroll
    for (int nj = 0; nj < 2; ++nj) {
        const short* wr = Ws + (size_t)(c0 + nj * 16 + lr) * 512;
        #pragma unroll
        for (int ks = 0; ks < 16; ++ks)
            Bf[nj][ks] = *(const bfrag*)(wr + ks * 32 + lg * 8);
    }
    f32x4 acc[4][2];
    #pragma unroll
    for (int i = 0; i < 4; ++i)
        #pragma unroll
        for (int j = 0; j < 2; ++j)
            #pragma unroll
            for (int r = 0; r < 4; ++r) acc[i][j][r] = 0.f;

    const short* Gs = (const short*)G;
    #pragma unroll
    for (int ks = 0; ks < 16; ++ks) {
        bfrag a[4];
        #pragma unroll
        for (int mi = 0; mi < 4; ++mi)
            a[mi] = *(const bfrag*)(Gs + (size_t)(px0 + mi * 16 + lr) * 512 + ks * 32 + lg * 8);
        #pragma unroll
        for (int mi = 0; mi < 4; ++mi)
            #pragma unroll
            for (int nj = 0; nj < 2; ++nj)
                acc[mi][nj] = __builtin_amdgcn_mfma_f32_16x16x32_bf16(a[mi], Bf[nj][ks], acc[mi][nj], 0, 0, 0);
    }
    #pragma unroll
    for (int mi = 0; mi < 4; ++mi)
        #pragma unroll
        for (int nj = 0; nj < 2; ++nj)
            #pragma unroll
            for (int r = 0; r < 4; ++r) {
                const int p = px0 + mi * 16 + lg * 4 + r;
                const int c = c0 + nj * 16 + lr;
                const int b = p / HW, hw = p % HW;
                const size_t idx = ((size_t)b * C + c) * HW + hw;
                Outp[idx] = __bfloat162float(X1[idx]) + acc[mi][nj][r];
            }
}

extern "C" void kernel_launch(void* const* d_in, const int* in_sizes, int n_in,
                              void* d_out, int out_size, void* d_ws, size_t ws_size,
                              hipStream_t stream) {
    (void)in_sizes; (void)n_in; (void)out_size; (void)ws_size;
    const float* x     = (const float*)d_in[0];
    const float* mask  = (const float*)d_in[1];
    const float* edge  = (const float*)d_in[2];
    const float* ln1w  = (const float*)d_in[3];
    const float* ln1b  = (const float*)d_in[4];
    const float* Wq    = (const float*)d_in[5];
    const float* Wk    = (const float*)d_in[6];
    const float* Wv    = (const float*)d_in[7];
    const float* ln2w  = (const float*)d_in[8];
    const float* ln2b  = (const float*)d_in[9];
    const float* w_in  = (const float*)d_in[10];
    const float* w_dw  = (const float*)d_in[11];
    const float* w_out = (const float*)d_in[12];
    float* out = (float*)d_out;

    char* ws = (char*)d_ws;
    // persistent: [0, 7.93M) x1 bf16 ; [7.93M, 15.86M) xn2 bf16 ;
    // [15.86M, 47.58M) u_half bf16 ; [47.58M, 79.30M) g bf16. Total = 79,298,560 B.
    __hip_bfloat16* x1  = (__hip_bfloat16*)(ws + 0);
    __hip_bfloat16* xn2 = (__hip_bfloat16*)(ws + 7929856);
    __hip_bfloat16* uh  = (__hip_bfloat16*)(ws + 15859712);
    __hip_bfloat16* g   = (__hip_bfloat16*)(ws + 47579136);
    // transient (dead before u_half/g are written):
    __hip_bfloat16* qb  = (__hip_bfloat16*)(ws + 15859712);
    __hip_bfloat16* kb  = (__hip_bfloat16*)(ws + 23789568);
    __hip_bfloat16* vb  = (__hip_bfloat16*)(ws + 31719424);
    __hip_bfloat16* eb  = (__hip_bfloat16*)(ws + 39649280);
    __hip_bfloat16* xnm = (__hip_bfloat16*)(ws + 47579136);
    __hip_bfloat16* wob = (__hip_bfloat16*)(ws + 15859712); // after dw passes done

    k_pre<<<968, 256, 0, stream>>>(x, mask, edge, ln1w, ln1b, xnm, eb);
    k_gemm128<<<dim3(121, 1), 512, 0, stream>>>(eb,  Wq, qb, 128, -1);
    k_gemm128<<<dim3(121, 1), 512, 0, stream>>>(xnm, Wk, kb, 128, -1);
    k_gemm128<<<dim3(121, 1), 512, 0, stream>>>(xnm, Wv, vb, 128, -1);
    k_attn2<<<968, 256, 0, stream>>>(qb, kb, vb, x, x1);
    k_ln2<<<968, 256, 0, stream>>>(x1, ln2w, ln2b, xn2);
    k_gemm128<<<dim3(121, 4), 512, 0, stream>>>(xn2, w_in, uh, 512, 0);
    k_dw<<<352, 256, 0, stream>>>(uh, w_dw, g, 0);
    k_gemm128<<<dim3(121, 4), 512, 0, stream>>>(xn2, w_in, uh, 512, 1);
    k_dw<<<352, 256, 0, stream>>>(uh, w_dw, g, 1);
    k_cvt<<<256, 256, 0, stream>>>(w_out, wob, 128 * 512);
    k_gemm512<<<dim3(121, 2), 512, 0, stream>>>(g, wob, x1, out);
}

// Round 3
// 279.447 us; speedup vs baseline: 4.7059x; 1.9468x over previous
//
#include <hip/hip_runtime.h>
#include <hip/hip_bf16.h>
#include <math.h>

#define BATCH 4
#define C 128
#define H 88
#define W 88
#define HW 7744
#define NPIX 30976   // BATCH*HW
#define HALF 44
#define HID 512

typedef __attribute__((ext_vector_type(8))) short bfrag;   // 8 x bf16 (4 VGPR)
typedef __attribute__((ext_vector_type(4))) float f32x4;

__device__ __forceinline__ short f2bf(float f) {
    union { __hip_bfloat16 b; unsigned short u; } cv;
    cv.b = __float2bfloat16(f);
    return (short)cv.u;
}
__device__ __forceinline__ float bf2f(short s) {
    union { unsigned int u; float f; } cv;
    cv.u = ((unsigned int)(unsigned short)s) << 16;
    return cv.f;
}

// bilinear 2x upsample taps (jax half-pixel, clamped)
__device__ __forceinline__ void up_taps(int i, int& j0, int& j1, float& w0, float& w1) {
    float f = 0.5f * i - 0.25f;
    int i0 = (int)floorf(f);
    float fr = f - (float)i0;
    j0 = max(i0, 0);
    j1 = min(i0 + 1, HALF - 1);
    w0 = 1.f - fr;
    w1 = fr;
}

// ---------------- K1: LN1+mask -> xnm (bf16 pixel-major); edge upsample -> e ----------------
__global__ __launch_bounds__(256) void k_pre(
    const float* __restrict__ x, const float* __restrict__ mask,
    const float* __restrict__ edge, const float* __restrict__ ln1w,
    const float* __restrict__ ln1b,
    __hip_bfloat16* __restrict__ xnm, __hip_bfloat16* __restrict__ eo)
{
    __shared__ float xT[C][32];
    __shared__ float eT[C][32];
    const int tid = threadIdx.x, s = tid >> 5, px = tid & 31;
    const int blk = blockIdx.x, b = blk / 242, hw0 = (blk % 242) * 32;
    const int hw = hw0 + px, hi = hw / W, wi = hw % W;

    int y0, y1, x0, x1c; float wy0, wy1, wx0, wx1;
    up_taps(hi, y0, y1, wy0, wy1);
    up_taps(wi, x0, x1c, wx0, wx1);

    const float* mb = mask + (size_t)b * HALF * HALF;
    const float mval = wy0 * (wx0 * mb[y0 * HALF + x0] + wx1 * mb[y0 * HALF + x1c])
                     + wy1 * (wx0 * mb[y1 * HALF + x0] + wx1 * mb[y1 * HALF + x1c]);

    const float* xb = x + (size_t)b * C * HW;
    const float* eb = edge + (size_t)b * C * HALF * HALF;
    for (int c = s; c < C; c += 8) {
        xT[c][px] = xb[c * HW + hw];
        const float* ec = eb + c * HALF * HALF;
        eT[c][px] = wy0 * (wx0 * ec[y0 * HALF + x0] + wx1 * ec[y0 * HALF + x1c])
                  + wy1 * (wx0 * ec[y1 * HALF + x0] + wx1 * ec[y1 * HALF + x1c]);
    }
    __syncthreads();
    float sum = 0.f, sq = 0.f;
    for (int c = 0; c < C; ++c) { float t = xT[c][px]; sum += t; sq += t * t; }
    const float mu = sum * (1.f / C);
    const float rstd = rsqrtf(sq * (1.f / C) - mu * mu + 1e-5f);
    __syncthreads();
    for (int c = s; c < C; c += 8)
        xT[c][px] = ((xT[c][px] - mu) * rstd * ln1w[c] + ln1b[c]) * mval;
    __syncthreads();

    const size_t gp = (size_t)b * HW + hw;
    const int cs = s * 16;
    bfrag r0, r1;
    #pragma unroll
    for (int i = 0; i < 8; ++i) { r0[i] = f2bf(xT[cs + i][px]); r1[i] = f2bf(xT[cs + 8 + i][px]); }
    *(bfrag*)((short*)xnm + gp * C + cs) = r0;
    *(bfrag*)((short*)xnm + gp * C + cs + 8) = r1;
    #pragma unroll
    for (int i = 0; i < 8; ++i) { r0[i] = f2bf(eT[cs + i][px]); r1[i] = f2bf(eT[cs + 8 + i][px]); }
    *(bfrag*)((short*)eo + gp * C + cs) = r0;
    *(bfrag*)((short*)eo + gp * C + cs + 8) = r1;
}

// ---------------- fused QKV GEMM (K=128): blockIdx.y selects (A, W, Out) ----------------
__global__ __launch_bounds__(512, 2) void k_gemmQKV(
    const __hip_bfloat16* __restrict__ eb, const __hip_bfloat16* __restrict__ xnm,
    const float* __restrict__ Wq, const float* __restrict__ Wk, const float* __restrict__ Wv,
    __hip_bfloat16* __restrict__ qb, __hip_bfloat16* __restrict__ kb,
    __hip_bfloat16* __restrict__ vb)
{
    const __hip_bfloat16* A; const float* Wf; __hip_bfloat16* Out;
    if (blockIdx.y == 0)      { A = eb;  Wf = Wq; Out = qb; }
    else if (blockIdx.y == 1) { A = xnm; Wf = Wk; Out = kb; }
    else                      { A = xnm; Wf = Wv; Out = vb; }

    const int lane = threadIdx.x & 63, wv = threadIdx.x >> 6;
    const int wm = wv & 3, wn = wv >> 2;          // wn 0..1
    const int px0 = blockIdx.x * 256 + wm * 64;
    const int c0 = wn * 64;
    const int lr = lane & 15, lg = lane >> 4;

    bfrag Bf[4][4];
    #pragma unroll
    for (int nj = 0; nj < 4; ++nj) {
        const float* wr = Wf + (size_t)(c0 + nj * 16 + lr) * 128;
        #pragma unroll
        for (int ks = 0; ks < 4; ++ks) {
            const float4 f0 = *(const float4*)(wr + ks * 32 + lg * 8);
            const float4 f1 = *(const float4*)(wr + ks * 32 + lg * 8 + 4);
            bfrag t;
            t[0] = f2bf(f0.x); t[1] = f2bf(f0.y); t[2] = f2bf(f0.z); t[3] = f2bf(f0.w);
            t[4] = f2bf(f1.x); t[5] = f2bf(f1.y); t[6] = f2bf(f1.z); t[7] = f2bf(f1.w);
            Bf[nj][ks] = t;
        }
    }
    f32x4 acc[4][4];
    #pragma unroll
    for (int i = 0; i < 4; ++i)
        #pragma unroll
        for (int j = 0; j < 4; ++j)
            #pragma unroll
            for (int r = 0; r < 4; ++r) acc[i][j][r] = 0.f;

    const short* As = (const short*)A;
    #pragma unroll
    for (int ks = 0; ks < 4; ++ks) {
        bfrag a[4];
        #pragma unroll
        for (int mi = 0; mi < 4; ++mi)
            a[mi] = *(const bfrag*)(As + (size_t)(px0 + mi * 16 + lr) * 128 + ks * 32 + lg * 8);
        #pragma unroll
        for (int mi = 0; mi < 4; ++mi)
            #pragma unroll
            for (int nj = 0; nj < 4; ++nj)
                acc[mi][nj] = __builtin_amdgcn_mfma_f32_16x16x32_bf16(a[mi], Bf[nj][ks], acc[mi][nj], 0, 0, 0);
    }
    short* Os = (short*)Out;
    #pragma unroll
    for (int mi = 0; mi < 4; ++mi)
        #pragma unroll
        for (int nj = 0; nj < 4; ++nj)
            #pragma unroll
            for (int r = 0; r < 4; ++r) {
                const int p = px0 + mi * 16 + lg * 4 + r;
                const int c = c0 + nj * 16 + lr;
                Os[(size_t)p * 128 + c] = f2bf(acc[mi][nj][r]);
            }
}

// ---------------- GEMM K=128: Out[p][lc] = sum_k A[p][k] * Wf[gc][k]  (MFMA bf16) ----------------
__global__ __launch_bounds__(512, 2) void k_gemm128(
    const __hip_bfloat16* __restrict__ A,   // [NPIX][128] bf16
    const float* __restrict__ Wf,           // [*][128] fp32
    __hip_bfloat16* __restrict__ Out,       // [NPIX][outStride] bf16
    int outStride, int passMode)
{
    const int lane = threadIdx.x & 63, wv = threadIdx.x >> 6;
    const int wm = wv & 3, wn = wv >> 2;
    const int px0 = blockIdx.x * 256 + wm * 64;
    const int lc0 = blockIdx.y * 128 + wn * 64;
    int gc0 = lc0;
    if (passMode >= 0)
        gc0 = (lc0 < 256) ? passMode * 256 + lc0 : 512 + passMode * 256 + (lc0 - 256);
    const int lr = lane & 15, lg = lane >> 4;

    bfrag Bf[4][4];
    #pragma unroll
    for (int nj = 0; nj < 4; ++nj) {
        const float* wr = Wf + (size_t)(gc0 + nj * 16 + lr) * 128;
        #pragma unroll
        for (int ks = 0; ks < 4; ++ks) {
            const float4 f0 = *(const float4*)(wr + ks * 32 + lg * 8);
            const float4 f1 = *(const float4*)(wr + ks * 32 + lg * 8 + 4);
            bfrag t;
            t[0] = f2bf(f0.x); t[1] = f2bf(f0.y); t[2] = f2bf(f0.z); t[3] = f2bf(f0.w);
            t[4] = f2bf(f1.x); t[5] = f2bf(f1.y); t[6] = f2bf(f1.z); t[7] = f2bf(f1.w);
            Bf[nj][ks] = t;
        }
    }
    f32x4 acc[4][4];
    #pragma unroll
    for (int i = 0; i < 4; ++i)
        #pragma unroll
        for (int j = 0; j < 4; ++j)
            #pragma unroll
            for (int r = 0; r < 4; ++r) acc[i][j][r] = 0.f;

    const short* As = (const short*)A;
    #pragma unroll
    for (int ks = 0; ks < 4; ++ks) {
        bfrag a[4];
        #pragma unroll
        for (int mi = 0; mi < 4; ++mi)
            a[mi] = *(const bfrag*)(As + (size_t)(px0 + mi * 16 + lr) * 128 + ks * 32 + lg * 8);
        #pragma unroll
        for (int mi = 0; mi < 4; ++mi)
            #pragma unroll
            for (int nj = 0; nj < 4; ++nj)
                acc[mi][nj] = __builtin_amdgcn_mfma_f32_16x16x32_bf16(a[mi], Bf[nj][ks], acc[mi][nj], 0, 0, 0);
    }
    short* Os = (short*)Out;
    #pragma unroll
    for (int mi = 0; mi < 4; ++mi)
        #pragma unroll
        for (int nj = 0; nj < 4; ++nj)
            #pragma unroll
            for (int r = 0; r < 4; ++r) {
                const int p = px0 + mi * 16 + lg * 4 + r;
                const int c = lc0 + nj * 16 + lr;
                Os[(size_t)p * outStride + c] = f2bf(acc[mi][nj][r]);
            }
}

// ---------------- Attention: per-pixel 64x64 softmax; x1 = x + out (bf16, scattered) ----------------
__global__ __launch_bounds__(256) void k_attn2(
    const __hip_bfloat16* __restrict__ Q, const __hip_bfloat16* __restrict__ Kb,
    const __hip_bfloat16* __restrict__ Vb, const float* __restrict__ x,
    __hip_bfloat16* __restrict__ x1)
{
    __shared__ float qT[C][32], kT[C][32], vT[C][32];
    const int tid = threadIdx.x, s = tid >> 5, px = tid & 31;
    const int blk = blockIdx.x, b = blk / 242, hw0 = (blk % 242) * 32;
    const int hw = hw0 + px, hi = hw / W, wi = hw % W;
    const size_t gp = (size_t)b * HW + hw;
    const int cs = s * 16;
    {
        const short* qs = (const short*)Q + gp * C + cs;
        const short* ks = (const short*)Kb + gp * C + cs;
        const short* vs = (const short*)Vb + gp * C + cs;
        bfrag a0 = *(const bfrag*)qs, a1 = *(const bfrag*)(qs + 8);
        bfrag b0 = *(const bfrag*)ks, b1 = *(const bfrag*)(ks + 8);
        bfrag c0 = *(const bfrag*)vs, c1 = *(const bfrag*)(vs + 8);
        #pragma unroll
        for (int i = 0; i < 8; ++i) {
            qT[cs + i][px] = bf2f(a0[i]); qT[cs + 8 + i][px] = bf2f(a1[i]);
            kT[cs + i][px] = bf2f(b0[i]); kT[cs + 8 + i][px] = bf2f(b1[i]);
            vT[cs + i][px] = bf2f(c0[i]); vT[cs + 8 + i][px] = bf2f(c1[i]);
        }
    }
    __syncthreads();

    const int r_ = hi >> 2, col = wi >> 2, n = (hi & 3) * 4 + (wi & 3);
    const size_t bbase = (size_t)b * C * HW;
    const int wbase = r_ * 22 + col;
    for (int rr = 0; rr < 8; ++rr) {
        const int j = s + 8 * rr;
        const float q1v = qT[j][px], q2v = qT[64 + j][px];
        float dv[64];
        float mx = -1e30f;
        #pragma unroll
        for (int kk = 0; kk < 64; ++kk) {
            float d = (q1v * kT[kk][px] + q2v * kT[64 + kk][px]) * 0.125f;
            dv[kk] = d; mx = fmaxf(mx, d);
        }
        float ssum = 0.f;
        #pragma unroll
        for (int kk = 0; kk < 64; ++kk) { float e = __expf(dv[kk] - mx); dv[kk] = e; ssum += e; }
        const float inv = 1.f / ssum;
        float o1 = 0.f, o2 = 0.f;
        #pragma unroll
        for (int kk = 0; kk < 64; ++kk) { o1 += dv[kk] * vT[kk][px]; o2 += dv[kk] * vT[64 + kk][px]; }
        o1 *= inv; o2 *= inv;
        const int f1 = (n * C + j) * 484 + wbase;
        const int f2 = (n * C + 64 + j) * 484 + wbase;
        x1[bbase + f1] = __float2bfloat16(x[bbase + f1] + o1);
        x1[bbase + f2] = __float2bfloat16(x[bbase + f2] + o2);
    }
}

// ---------------- LN2: x1(bf16, ch-major) -> xn2 (bf16, pixel-major) ----------------
__global__ __launch_bounds__(256) void k_ln2(
    const __hip_bfloat16* __restrict__ x1, const float* __restrict__ ln2w,
    const float* __restrict__ ln2b, __hip_bfloat16* __restrict__ xn2)
{
    __shared__ float xT[C][32];
    const int tid = threadIdx.x, s = tid >> 5, px = tid & 31;
    const int blk = blockIdx.x, b = blk / 242, hw0 = (blk % 242) * 32;
    const int hw = hw0 + px;
    const __hip_bfloat16* xb = x1 + (size_t)b * C * HW;
    for (int c = s; c < C; c += 8) xT[c][px] = __bfloat162float(xb[c * HW + hw]);
    __syncthreads();
    float sum = 0.f, sq = 0.f;
    for (int c = 0; c < C; ++c) { float t = xT[c][px]; sum += t; sq += t * t; }
    const float mu = sum * (1.f / C);
    const float rstd = rsqrtf(sq * (1.f / C) - mu * mu + 1e-5f);
    __syncthreads();
    for (int c = s; c < C; c += 8)
        xT[c][px] = (xT[c][px] - mu) * rstd * ln2w[c] + ln2b[c];
    __syncthreads();
    const size_t gp = (size_t)b * HW + hw;
    const int cs = s * 16;
    bfrag r0, r1;
    #pragma unroll
    for (int i = 0; i < 8; ++i) { r0[i] = f2bf(xT[cs + i][px]); r1[i] = f2bf(xT[cs + 8 + i][px]); }
    *(bfrag*)((short*)xn2 + gp * C + cs) = r0;
    *(bfrag*)((short*)xn2 + gp * C + cs + 8) = r1;
}

// ---------------- depthwise 3x3 + gelu gate, parallel rolling-window version ----------------
// block = (b, row, 8-px segment); thread = channel-pair cl (0..255)
__global__ __launch_bounds__(256) void k_dw(
    const __hip_bfloat16* __restrict__ U,   // [NPIX][512] (t1: cols 0..255, t2: 256..511)
    const float* __restrict__ wdw,          // [1024][9]
    __hip_bfloat16* __restrict__ Gout,      // [NPIX][512]
    int pass)
{
    const int cl = threadIdx.x;
    const int blk = blockIdx.x;             // b*H*11 + hi*11 + seg
    const int seg = blk % 11;
    const int hi = (blk / 11) % H;
    const int b = blk / (11 * H);
    const int w0 = seg * 8;
    const int gc1 = pass * 256 + cl, gc2 = 512 + gc1;

    float w1[9], w2[9];
    #pragma unroll
    for (int t = 0; t < 9; ++t) { w1[t] = wdw[gc1 * 9 + t]; w2[t] = wdw[gc2 * 9 + t]; }

    const short* Us = (const short*)U;
    const size_t base = (size_t)b * HW;
    const bool r0ok = (hi - 1) >= 0, r2ok = (hi + 1) < H;

    // column slots [3][row 0..2]
    float A1[3][3], A2[3][3];

    #define LOADCOL(slot, wc)  do {                                              \
        if ((unsigned)(wc) >= W) {                                               \
            A1[slot][0]=A1[slot][1]=A1[slot][2]=0.f;                             \
            A2[slot][0]=A2[slot][1]=A2[slot][2]=0.f;                             \
        } else {                                                                 \
            size_t p1 = base + (size_t)(hi - 1) * W + (wc);                      \
            size_t p2 = base + (size_t)hi * W + (wc);                            \
            size_t p3 = base + (size_t)(hi + 1) * W + (wc);                      \
            A1[slot][0] = r0ok ? bf2f(Us[p1 * 512 + cl]) : 0.f;                  \
            A2[slot][0] = r0ok ? bf2f(Us[p1 * 512 + 256 + cl]) : 0.f;            \
            A1[slot][1] = bf2f(Us[p2 * 512 + cl]);                               \
            A2[slot][1] = bf2f(Us[p2 * 512 + 256 + cl]);                         \
            A1[slot][2] = r2ok ? bf2f(Us[p3 * 512 + cl]) : 0.f;                  \
            A2[slot][2] = r2ok ? bf2f(Us[p3 * 512 + 256 + cl]) : 0.f;            \
        } } while (0)

    LOADCOL(0, w0 - 1);
    LOADCOL(1, w0);

    #pragma unroll
    for (int i = 0; i < 8; ++i) {
        const int wi = w0 + i;
        const int sl = i % 3, sm = (i + 1) % 3, sr = (i + 2) % 3;
        LOADCOL(sr, wi + 1);
        float t1 = 0.f, t2 = 0.f;
        #pragma unroll
        for (int r = 0; r < 3; ++r) {
            t1 += w1[r * 3 + 0] * A1[sl][r] + w1[r * 3 + 1] * A1[sm][r] + w1[r * 3 + 2] * A1[sr][r];
            t2 += w2[r * 3 + 0] * A2[sl][r] + w2[r * 3 + 1] * A2[sm][r] + w2[r * 3 + 2] * A2[sr][r];
        }
        const float gl = 0.5f * t1 * (1.f + erff(t1 * 0.70710678118654752f));
        Gout[(base + (size_t)hi * W + wi) * 512 + pass * 256 + cl] = __float2bfloat16(gl * t2);
    }
    #undef LOADCOL
}

// ---------------- small cvt: w_out fp32 -> bf16 ----------------
__global__ __launch_bounds__(256) void k_cvt(const float* __restrict__ src,
                                             __hip_bfloat16* __restrict__ dst, int n) {
    int i = blockIdx.x * 256 + threadIdx.x;
    if (i < n) dst[i] = __float2bfloat16(src[i]);
}

// ---------------- GEMM K=512 + residual: out = x1 + w_out @ g ----------------
__global__ __launch_bounds__(512, 2) void k_gemm512(
    const __hip_bfloat16* __restrict__ G,   // [NPIX][512]
    const __hip_bfloat16* __restrict__ Wob, // [128][512] bf16
    const __hip_bfloat16* __restrict__ X1,  // [B][C][HW] bf16
    float* __restrict__ Outp)               // [B][C][HW] f32
{
    const int lane = threadIdx.x & 63, wv = threadIdx.x >> 6;
    const int wm = wv & 3, wn = wv >> 2;    // wn 0..1
    const int px0 = blockIdx.x * 256 + wm * 64;
    const int c0 = blockIdx.y * 64 + wn * 32;
    const int lr = lane & 15, lg = lane >> 4;
    const short* Ws = (const short*)Wob;
    bfrag Bf[2][16];
    #pragma unroll
    for (int nj = 0; nj < 2; ++nj) {
        const short* wr = Ws + (size_t)(c0 + nj * 16 + lr) * 512;
        #pragma unroll
        for (int ks = 0; ks < 16; ++ks)
            Bf[nj][ks] = *(const bfrag*)(wr + ks * 32 + lg * 8);
    }
    f32x4 acc[4][2];
    #pragma unroll
    for (int i = 0; i < 4; ++i)
        #pragma unroll
        for (int j = 0; j < 2; ++j)
            #pragma unroll
            for (int r = 0; r < 4; ++r) acc[i][j][r] = 0.f;

    const short* Gs = (const short*)G;
    #pragma unroll
    for (int ks = 0; ks < 16; ++ks) {
        bfrag a[4];
        #pragma unroll
        for (int mi = 0; mi < 4; ++mi)
            a[mi] = *(const bfrag*)(Gs + (size_t)(px0 + mi * 16 + lr) * 512 + ks * 32 + lg * 8);
        #pragma unroll
        for (int mi = 0; mi < 4; ++mi)
            #pragma unroll
            for (int nj = 0; nj < 2; ++nj)
                acc[mi][nj] = __builtin_amdgcn_mfma_f32_16x16x32_bf16(a[mi], Bf[nj][ks], acc[mi][nj], 0, 0, 0);
    }
    #pragma unroll
    for (int mi = 0; mi < 4; ++mi)
        #pragma unroll
        for (int nj = 0; nj < 2; ++nj)
            #pragma unroll
            for (int r = 0; r < 4; ++r) {
                const int p = px0 + mi * 16 + lg * 4 + r;
                const int c = c0 + nj * 16 + lr;
                const int b = p / HW, hw = p % HW;
                const size_t idx = ((size_t)b * C + c) * HW + hw;
                Outp[idx] = __bfloat162float(X1[idx]) + acc[mi][nj][r];
            }
}

extern "C" void kernel_launch(void* const* d_in, const int* in_sizes, int n_in,
                              void* d_out, int out_size, void* d_ws, size_t ws_size,
                              hipStream_t stream) {
    (void)in_sizes; (void)n_in; (void)out_size; (void)ws_size;
    const float* x     = (const float*)d_in[0];
    const float* mask  = (const float*)d_in[1];
    const float* edge  = (const float*)d_in[2];
    const float* ln1w  = (const float*)d_in[3];
    const float* ln1b  = (const float*)d_in[4];
    const float* Wq    = (const float*)d_in[5];
    const float* Wk    = (const float*)d_in[6];
    const float* Wv    = (const float*)d_in[7];
    const float* ln2w  = (const float*)d_in[8];
    const float* ln2b  = (const float*)d_in[9];
    const float* w_in  = (const float*)d_in[10];
    const float* w_dw  = (const float*)d_in[11];
    const float* w_out = (const float*)d_in[12];
    float* out = (float*)d_out;

    char* ws = (char*)d_ws;
    // persistent: [0, 7.93M) x1 bf16 ; [7.93M, 15.86M) xn2 bf16 ;
    // [15.86M, 47.58M) u_half bf16 ; [47.58M, 79.30M) g bf16. Total = 79,298,560 B.
    __hip_bfloat16* x1  = (__hip_bfloat16*)(ws + 0);
    __hip_bfloat16* xn2 = (__hip_bfloat16*)(ws + 7929856);
    __hip_bfloat16* uh  = (__hip_bfloat16*)(ws + 15859712);
    __hip_bfloat16* g   = (__hip_bfloat16*)(ws + 47579136);
    // transient (dead before u_half/g are written):
    __hip_bfloat16* qb  = (__hip_bfloat16*)(ws + 15859712);
    __hip_bfloat16* kb  = (__hip_bfloat16*)(ws + 23789568);
    __hip_bfloat16* vb  = (__hip_bfloat16*)(ws + 31719424);
    __hip_bfloat16* eb  = (__hip_bfloat16*)(ws + 39649280);
    __hip_bfloat16* xnm = (__hip_bfloat16*)(ws + 47579136);
    __hip_bfloat16* wob = (__hip_bfloat16*)(ws + 15859712); // after dw passes done

    k_pre<<<968, 256, 0, stream>>>(x, mask, edge, ln1w, ln1b, xnm, eb);
    k_gemmQKV<<<dim3(121, 3), 512, 0, stream>>>(eb, xnm, Wq, Wk, Wv, qb, kb, vb);
    k_attn2<<<968, 256, 0, stream>>>(qb, kb, vb, x, x1);
    k_ln2<<<968, 256, 0, stream>>>(x1, ln2w, ln2b, xn2);
    k_gemm128<<<dim3(121, 4), 512, 0, stream>>>(xn2, w_in, uh, 512, 0);
    k_dw<<<3872, 256, 0, stream>>>(uh, w_dw, g, 0);
    k_gemm128<<<dim3(121, 4), 512, 0, stream>>>(xn2, w_in, uh, 512, 1);
    k_dw<<<3872, 256, 0, stream>>>(uh, w_dw, g, 1);
    k_cvt<<<256, 256, 0, stream>>>(w_out, wob, 128 * 512);
    k_gemm512<<<dim3(121, 2), 512, 0, stream>>>(g, wob, x1, out);
}

// Round 4
// 245.849 us; speedup vs baseline: 5.3490x; 1.1367x over previous
//
#include <hip/hip_runtime.h>
#include <hip/hip_bf16.h>
#include <math.h>

#define BATCH 4
#define C 128
#define H 88
#define W 88
#define HW 7744
#define NPIX 30976   // BATCH*HW
#define HALF 44
#define HID 512

typedef __attribute__((ext_vector_type(8))) short bfrag;   // 8 x bf16 (4 VGPR)
typedef __attribute__((ext_vector_type(4))) float f32x4;

__device__ __forceinline__ short f2bf(float f) {
    union { __hip_bfloat16 b; unsigned short u; } cv;
    cv.b = __float2bfloat16(f);
    return (short)cv.u;
}
__device__ __forceinline__ float bf2f(short s) {
    union { unsigned int u; float f; } cv;
    cv.u = ((unsigned int)(unsigned short)s) << 16;
    return cv.f;
}

// bilinear 2x upsample taps (jax half-pixel, clamped)
__device__ __forceinline__ void up_taps(int i, int& j0, int& j1, float& w0, float& w1) {
    float f = 0.5f * i - 0.25f;
    int i0 = (int)floorf(f);
    float fr = f - (float)i0;
    j0 = max(i0, 0);
    j1 = min(i0 + 1, HALF - 1);
    w0 = 1.f - fr;
    w1 = fr;
}

// ---------------- K1: LN1+mask -> xnm (bf16 pixel-major); edge upsample -> e ----------------
__global__ __launch_bounds__(256) void k_pre(
    const float* __restrict__ x, const float* __restrict__ mask,
    const float* __restrict__ edge, const float* __restrict__ ln1w,
    const float* __restrict__ ln1b,
    __hip_bfloat16* __restrict__ xnm, __hip_bfloat16* __restrict__ eo)
{
    __shared__ float redS[8][32], redQ[8][32];
    const int tid = threadIdx.x, s = tid >> 5, px = tid & 31;
    const int blk = blockIdx.x, b = blk / 242, hw0 = (blk % 242) * 32;
    const int hw = hw0 + px, hi = hw / W, wi = hw % W;
    const int cs = s * 16;

    int y0, y1, x0, x1c; float wy0, wy1, wx0, wx1;
    up_taps(hi, y0, y1, wy0, wy1);
    up_taps(wi, x0, x1c, wx0, wx1);

    const float* mb = mask + (size_t)b * HALF * HALF;
    const float mval = wy0 * (wx0 * mb[y0 * HALF + x0] + wx1 * mb[y0 * HALF + x1c])
                     + wy1 * (wx0 * mb[y1 * HALF + x0] + wx1 * mb[y1 * HALF + x1c]);

    const float* xb = x + (size_t)b * C * HW;
    const float* ebs = edge + (size_t)b * C * HALF * HALF;
    float xr[16], er[16];
    float sum = 0.f, sq = 0.f;
    #pragma unroll
    for (int i = 0; i < 16; ++i) {
        const int c = cs + i;
        const float t = xb[c * HW + hw];
        xr[i] = t; sum += t; sq += t * t;
        const float* ec = ebs + c * HALF * HALF;
        er[i] = wy0 * (wx0 * ec[y0 * HALF + x0] + wx1 * ec[y0 * HALF + x1c])
              + wy1 * (wx0 * ec[y1 * HALF + x0] + wx1 * ec[y1 * HALF + x1c]);
    }
    redS[s][px] = sum; redQ[s][px] = sq;
    __syncthreads();
    float tsum = 0.f, tsq = 0.f;
    #pragma unroll
    for (int i = 0; i < 8; ++i) { tsum += redS[i][px]; tsq += redQ[i][px]; }
    const float mu = tsum * (1.f / C);
    const float rstd = rsqrtf(tsq * (1.f / C) - mu * mu + 1e-5f);

    const size_t gp = (size_t)b * HW + hw;
    bfrag r0, r1;
    #pragma unroll
    for (int i = 0; i < 8; ++i) {
        r0[i] = f2bf(((xr[i] - mu) * rstd * ln1w[cs + i] + ln1b[cs + i]) * mval);
        r1[i] = f2bf(((xr[8 + i] - mu) * rstd * ln1w[cs + 8 + i] + ln1b[cs + 8 + i]) * mval);
    }
    *(bfrag*)((short*)xnm + gp * C + cs) = r0;
    *(bfrag*)((short*)xnm + gp * C + cs + 8) = r1;
    #pragma unroll
    for (int i = 0; i < 8; ++i) { r0[i] = f2bf(er[i]); r1[i] = f2bf(er[8 + i]); }
    *(bfrag*)((short*)eo + gp * C + cs) = r0;
    *(bfrag*)((short*)eo + gp * C + cs + 8) = r1;
}

// ---------------- fused QKV GEMM (K=128): blockIdx.y selects (A, W, Out) ----------------
__global__ __launch_bounds__(512, 2) void k_gemmQKV(
    const __hip_bfloat16* __restrict__ eb, const __hip_bfloat16* __restrict__ xnm,
    const float* __restrict__ Wq, const float* __restrict__ Wk, const float* __restrict__ Wv,
    __hip_bfloat16* __restrict__ qb, __hip_bfloat16* __restrict__ kb,
    __hip_bfloat16* __restrict__ vb)
{
    const __hip_bfloat16* A; const float* Wf; __hip_bfloat16* Out;
    if (blockIdx.y == 0)      { A = eb;  Wf = Wq; Out = qb; }
    else if (blockIdx.y == 1) { A = xnm; Wf = Wk; Out = kb; }
    else                      { A = xnm; Wf = Wv; Out = vb; }

    const int lane = threadIdx.x & 63, wv = threadIdx.x >> 6;
    const int wm = wv & 3, wn = wv >> 2;          // wn 0..1
    const int px0 = blockIdx.x * 256 + wm * 64;
    const int c0 = wn * 64;
    const int lr = lane & 15, lg = lane >> 4;

    bfrag Bf[4][4];
    #pragma unroll
    for (int nj = 0; nj < 4; ++nj) {
        const float* wr = Wf + (size_t)(c0 + nj * 16 + lr) * 128;
        #pragma unroll
        for (int ks = 0; ks < 4; ++ks) {
            const float4 f0 = *(const float4*)(wr + ks * 32 + lg * 8);
            const float4 f1 = *(const float4*)(wr + ks * 32 + lg * 8 + 4);
            bfrag t;
            t[0] = f2bf(f0.x); t[1] = f2bf(f0.y); t[2] = f2bf(f0.z); t[3] = f2bf(f0.w);
            t[4] = f2bf(f1.x); t[5] = f2bf(f1.y); t[6] = f2bf(f1.z); t[7] = f2bf(f1.w);
            Bf[nj][ks] = t;
        }
    }
    f32x4 acc[4][4];
    #pragma unroll
    for (int i = 0; i < 4; ++i)
        #pragma unroll
        for (int j = 0; j < 4; ++j)
            #pragma unroll
            for (int r = 0; r < 4; ++r) acc[i][j][r] = 0.f;

    const short* As = (const short*)A;
    #pragma unroll
    for (int ks = 0; ks < 4; ++ks) {
        bfrag a[4];
        #pragma unroll
        for (int mi = 0; mi < 4; ++mi)
            a[mi] = *(const bfrag*)(As + (size_t)(px0 + mi * 16 + lr) * 128 + ks * 32 + lg * 8);
        #pragma unroll
        for (int mi = 0; mi < 4; ++mi)
            #pragma unroll
            for (int nj = 0; nj < 4; ++nj)
                acc[mi][nj] = __builtin_amdgcn_mfma_f32_16x16x32_bf16(a[mi], Bf[nj][ks], acc[mi][nj], 0, 0, 0);
    }
    short* Os = (short*)Out;
    #pragma unroll
    for (int mi = 0; mi < 4; ++mi)
        #pragma unroll
        for (int nj = 0; nj < 4; ++nj)
            #pragma unroll
            for (int r = 0; r < 4; ++r) {
                const int p = px0 + mi * 16 + lg * 4 + r;
                const int c = c0 + nj * 16 + lr;
                Os[(size_t)p * 128 + c] = f2bf(acc[mi][nj][r]);
            }
}

// ---------------- GEMM K=128: Out[p][lc] = sum_k A[p][k] * Wf[gc][k]  (MFMA bf16) ----------------
__global__ __launch_bounds__(512, 2) void k_gemm128(
    const __hip_bfloat16* __restrict__ A,   // [NPIX][128] bf16
    const float* __restrict__ Wf,           // [*][128] fp32
    __hip_bfloat16* __restrict__ Out,       // [NPIX][outStride] bf16
    int outStride, int passMode)
{
    const int lane = threadIdx.x & 63, wv = threadIdx.x >> 6;
    const int wm = wv & 3, wn = wv >> 2;
    const int px0 = blockIdx.x * 256 + wm * 64;
    const int lc0 = blockIdx.y * 128 + wn * 64;
    int gc0 = lc0;
    if (passMode >= 0)
        gc0 = (lc0 < 256) ? passMode * 256 + lc0 : 512 + passMode * 256 + (lc0 - 256);
    const int lr = lane & 15, lg = lane >> 4;

    bfrag Bf[4][4];
    #pragma unroll
    for (int nj = 0; nj < 4; ++nj) {
        const float* wr = Wf + (size_t)(gc0 + nj * 16 + lr) * 128;
        #pragma unroll
        for (int ks = 0; ks < 4; ++ks) {
            const float4 f0 = *(const float4*)(wr + ks * 32 + lg * 8);
            const float4 f1 = *(const float4*)(wr + ks * 32 + lg * 8 + 4);
            bfrag t;
            t[0] = f2bf(f0.x); t[1] = f2bf(f0.y); t[2] = f2bf(f0.z); t[3] = f2bf(f0.w);
            t[4] = f2bf(f1.x); t[5] = f2bf(f1.y); t[6] = f2bf(f1.z); t[7] = f2bf(f1.w);
            Bf[nj][ks] = t;
        }
    }
    f32x4 acc[4][4];
    #pragma unroll
    for (int i = 0; i < 4; ++i)
        #pragma unroll
        for (int j = 0; j < 4; ++j)
            #pragma unroll
            for (int r = 0; r < 4; ++r) acc[i][j][r] = 0.f;

    const short* As = (const short*)A;
    #pragma unroll
    for (int ks = 0; ks < 4; ++ks) {
        bfrag a[4];
        #pragma unroll
        for (int mi = 0; mi < 4; ++mi)
            a[mi] = *(const bfrag*)(As + (size_t)(px0 + mi * 16 + lr) * 128 + ks * 32 + lg * 8);
        #pragma unroll
        for (int mi = 0; mi < 4; ++mi)
            #pragma unroll
            for (int nj = 0; nj < 4; ++nj)
                acc[mi][nj] = __builtin_amdgcn_mfma_f32_16x16x32_bf16(a[mi], Bf[nj][ks], acc[mi][nj], 0, 0, 0);
    }
    short* Os = (short*)Out;
    #pragma unroll
    for (int mi = 0; mi < 4; ++mi)
        #pragma unroll
        for (int nj = 0; nj < 4; ++nj)
            #pragma unroll
            for (int r = 0; r < 4; ++r) {
                const int p = px0 + mi * 16 + lg * 4 + r;
                const int c = lc0 + nj * 16 + lr;
                Os[(size_t)p * outStride + c] = f2bf(acc[mi][nj][r]);
            }
}

// ---------------- Attention: streaming no-max softmax, kk-outer, kv interleaved LDS ----------------
__global__ __launch_bounds__(256) void k_attn2(
    const __hip_bfloat16* __restrict__ Q, const __hip_bfloat16* __restrict__ Kb,
    const __hip_bfloat16* __restrict__ Vb, const float* __restrict__ x,
    __hip_bfloat16* __restrict__ x1)
{
    __shared__ float kv[64][32][4];   // (k1,k2,v1,v2) per (kk, px) — 32 KB
    const int tid = threadIdx.x, s = tid >> 5, px = tid & 31;
    const int blk = blockIdx.x, b = blk / 242, hw0 = (blk % 242) * 32;
    const int hw = hw0 + px, hi = hw / W, wi = hw % W;
    const size_t gp = (size_t)b * HW + hw;
    const int cs = s * 16;

    // stage K,V (own 16 channels) into interleaved LDS
    {
        const short* ks_ = (const short*)Kb + gp * C + cs;
        const short* vs_ = (const short*)Vb + gp * C + cs;
        bfrag kb0 = *(const bfrag*)ks_, kb1 = *(const bfrag*)(ks_ + 8);
        bfrag vb0 = *(const bfrag*)vs_, vb1 = *(const bfrag*)(vs_ + 8);
        const int comp = (s < 4) ? 0 : 1;
        const int kkb = (s < 4) ? cs : cs - 64;
        #pragma unroll
        for (int i = 0; i < 8; ++i) {
            kv[kkb + i][px][comp]     = bf2f(kb0[i]);
            kv[kkb + i][px][comp + 2] = bf2f(vb0[i]);
            kv[kkb + 8 + i][px][comp]     = bf2f(kb1[i]);
            kv[kkb + 8 + i][px][comp + 2] = bf2f(vb1[i]);
        }
    }
    // q into registers (pre-scaled)
    float q1r[8], q2r[8];
    {
        const short* qs = (const short*)Q + gp * C;
        #pragma unroll
        for (int rr = 0; rr < 8; ++rr) {
            const int j = s + 8 * rr;
            q1r[rr] = bf2f(qs[j]) * 0.125f;
            q2r[rr] = bf2f(qs[64 + j]) * 0.125f;
        }
    }
    __syncthreads();

    float ssum[8], o1[8], o2[8];
    #pragma unroll
    for (int rr = 0; rr < 8; ++rr) { ssum[rr] = 0.f; o1[rr] = 0.f; o2[rr] = 0.f; }

    #pragma unroll 4
    for (int kk = 0; kk < 64; ++kk) {
        const f32x4 vv = *(const f32x4*)kv[kk][px];
        #pragma unroll
        for (int rr = 0; rr < 8; ++rr) {
            const float d = q1r[rr] * vv[0] + q2r[rr] * vv[1];
            const float e = __expf(d);   // |d| < ~0.4 by construction: no-max softmax safe
            ssum[rr] += e;
            o1[rr] += e * vv[2];
            o2[rr] += e * vv[3];
        }
    }

    const int r_ = hi >> 2, col = wi >> 2, n = (hi & 3) * 4 + (wi & 3);
    const size_t bbase = (size_t)b * C * HW;
    const int wbase = r_ * 22 + col;
    #pragma unroll
    for (int rr = 0; rr < 8; ++rr) {
        const int j = s + 8 * rr;
        const float inv = 1.f / ssum[rr];
        const int f1 = (n * C + j) * 484 + wbase;
        const int f2 = (n * C + 64 + j) * 484 + wbase;
        x1[bbase + f1] = __float2bfloat16(x[bbase + f1] + o1[rr] * inv);
        x1[bbase + f2] = __float2bfloat16(x[bbase + f2] + o2[rr] * inv);
    }
}

// ---------------- LN2: x1(bf16, ch-major) -> xn2 (bf16, pixel-major) ----------------
__global__ __launch_bounds__(256) void k_ln2(
    const __hip_bfloat16* __restrict__ x1, const float* __restrict__ ln2w,
    const float* __restrict__ ln2b, __hip_bfloat16* __restrict__ xn2)
{
    __shared__ float redS[8][32], redQ[8][32];
    const int tid = threadIdx.x, s = tid >> 5, px = tid & 31;
    const int blk = blockIdx.x, b = blk / 242, hw0 = (blk % 242) * 32;
    const int hw = hw0 + px;
    const int cs = s * 16;
    const __hip_bfloat16* xb = x1 + (size_t)b * C * HW;
    float xr[16];
    float sum = 0.f, sq = 0.f;
    #pragma unroll
    for (int i = 0; i < 16; ++i) {
        const float t = __bfloat162float(xb[(cs + i) * HW + hw]);
        xr[i] = t; sum += t; sq += t * t;
    }
    redS[s][px] = sum; redQ[s][px] = sq;
    __syncthreads();
    float tsum = 0.f, tsq = 0.f;
    #pragma unroll
    for (int i = 0; i < 8; ++i) { tsum += redS[i][px]; tsq += redQ[i][px]; }
    const float mu = tsum * (1.f / C);
    const float rstd = rsqrtf(tsq * (1.f / C) - mu * mu + 1e-5f);
    const size_t gp = (size_t)b * HW + hw;
    bfrag r0, r1;
    #pragma unroll
    for (int i = 0; i < 8; ++i) {
        r0[i] = f2bf((xr[i] - mu) * rstd * ln2w[cs + i] + ln2b[cs + i]);
        r1[i] = f2bf((xr[8 + i] - mu) * rstd * ln2w[cs + 8 + i] + ln2b[cs + 8 + i]);
    }
    *(bfrag*)((short*)xn2 + gp * C + cs) = r0;
    *(bfrag*)((short*)xn2 + gp * C + cs + 8) = r1;
}

// ---------------- depthwise 3x3 + gelu gate, parallel rolling-window version ----------------
__global__ __launch_bounds__(256) void k_dw(
    const __hip_bfloat16* __restrict__ U,   // [NPIX][512] (t1: cols 0..255, t2: 256..511)
    const float* __restrict__ wdw,          // [1024][9]
    __hip_bfloat16* __restrict__ Gout,      // [NPIX][512]
    int pass)
{
    const int cl = threadIdx.x;
    const int blk = blockIdx.x;             // b*H*11 + hi*11 + seg
    const int seg = blk % 11;
    const int hi = (blk / 11) % H;
    const int b = blk / (11 * H);
    const int w0 = seg * 8;
    const int gc1 = pass * 256 + cl, gc2 = 512 + gc1;

    float w1[9], w2[9];
    #pragma unroll
    for (int t = 0; t < 9; ++t) { w1[t] = wdw[gc1 * 9 + t]; w2[t] = wdw[gc2 * 9 + t]; }

    const short* Us = (const short*)U;
    const size_t base = (size_t)b * HW;
    const bool r0ok = (hi - 1) >= 0, r2ok = (hi + 1) < H;

    float A1[3][3], A2[3][3];

    #define LOADCOL(slot, wc)  do {                                              \
        if ((unsigned)(wc) >= W) {                                               \
            A1[slot][0]=A1[slot][1]=A1[slot][2]=0.f;                             \
            A2[slot][0]=A2[slot][1]=A2[slot][2]=0.f;                             \
        } else {                                                                 \
            size_t p1 = base + (size_t)(hi - 1) * W + (wc);                      \
            size_t p2 = base + (size_t)hi * W + (wc);                            \
            size_t p3 = base + (size_t)(hi + 1) * W + (wc);                      \
            A1[slot][0] = r0ok ? bf2f(Us[p1 * 512 + cl]) : 0.f;                  \
            A2[slot][0] = r0ok ? bf2f(Us[p1 * 512 + 256 + cl]) : 0.f;            \
            A1[slot][1] = bf2f(Us[p2 * 512 + cl]);                               \
            A2[slot][1] = bf2f(Us[p2 * 512 + 256 + cl]);                         \
            A1[slot][2] = r2ok ? bf2f(Us[p3 * 512 + cl]) : 0.f;                  \
            A2[slot][2] = r2ok ? bf2f(Us[p3 * 512 + 256 + cl]) : 0.f;            \
        } } while (0)

    LOADCOL(0, w0 - 1);
    LOADCOL(1, w0);

    #pragma unroll
    for (int i = 0; i < 8; ++i) {
        const int wi = w0 + i;
        const int sl = i % 3, sm = (i + 1) % 3, sr = (i + 2) % 3;
        LOADCOL(sr, wi + 1);
        float t1 = 0.f, t2 = 0.f;
        #pragma unroll
        for (int r = 0; r < 3; ++r) {
            t1 += w1[r * 3 + 0] * A1[sl][r] + w1[r * 3 + 1] * A1[sm][r] + w1[r * 3 + 2] * A1[sr][r];
            t2 += w2[r * 3 + 0] * A2[sl][r] + w2[r * 3 + 1] * A2[sm][r] + w2[r * 3 + 2] * A2[sr][r];
        }
        const float gl = 0.5f * t1 * (1.f + erff(t1 * 0.70710678118654752f));
        Gout[(base + (size_t)hi * W + wi) * 512 + pass * 256 + cl] = __float2bfloat16(gl * t2);
    }
    #undef LOADCOL
}

// ---------------- GEMM K=512 + residual: out = x1 + w_out @ g (w_out f32, cvt inline) ----------------
__global__ __launch_bounds__(512, 2) void k_gemm512(
    const __hip_bfloat16* __restrict__ G,   // [NPIX][512]
    const float* __restrict__ Wof,          // [128][512] f32
    const __hip_bfloat16* __restrict__ X1,  // [B][C][HW] bf16
    float* __restrict__ Outp)               // [B][C][HW] f32
{
    const int lane = threadIdx.x & 63, wv = threadIdx.x >> 6;
    const int wm = wv & 3, wn = wv >> 2;    // wn 0..1
    const int px0 = blockIdx.x * 256 + wm * 64;
    const int c0 = blockIdx.y * 64 + wn * 32;
    const int lr = lane & 15, lg = lane >> 4;
    bfrag Bf[2][16];
    #pragma unroll
    for (int nj = 0; nj < 2; ++nj) {
        const float* wr = Wof + (size_t)(c0 + nj * 16 + lr) * 512;
        #pragma unroll
        for (int ks = 0; ks < 16; ++ks) {
            const float4 f0 = *(const float4*)(wr + ks * 32 + lg * 8);
            const float4 f1 = *(const float4*)(wr + ks * 32 + lg * 8 + 4);
            bfrag t;
            t[0] = f2bf(f0.x); t[1] = f2bf(f0.y); t[2] = f2bf(f0.z); t[3] = f2bf(f0.w);
            t[4] = f2bf(f1.x); t[5] = f2bf(f1.y); t[6] = f2bf(f1.z); t[7] = f2bf(f1.w);
            Bf[nj][ks] = t;
        }
    }
    f32x4 acc[4][2];
    #pragma unroll
    for (int i = 0; i < 4; ++i)
        #pragma unroll
        for (int j = 0; j < 2; ++j)
            #pragma unroll
            for (int r = 0; r < 4; ++r) acc[i][j][r] = 0.f;

    const short* Gs = (const short*)G;
    #pragma unroll
    for (int ks = 0; ks < 16; ++ks) {
        bfrag a[4];
        #pragma unroll
        for (int mi = 0; mi < 4; ++mi)
            a[mi] = *(const bfrag*)(Gs + (size_t)(px0 + mi * 16 + lr) * 512 + ks * 32 + lg * 8);
        #pragma unroll
        for (int mi = 0; mi < 4; ++mi)
            #pragma unroll
            for (int nj = 0; nj < 2; ++nj)
                acc[mi][nj] = __builtin_amdgcn_mfma_f32_16x16x32_bf16(a[mi], Bf[nj][ks], acc[mi][nj], 0, 0, 0);
    }
    #pragma unroll
    for (int mi = 0; mi < 4; ++mi)
        #pragma unroll
        for (int nj = 0; nj < 2; ++nj)
            #pragma unroll
            for (int r = 0; r < 4; ++r) {
                const int p = px0 + mi * 16 + lg * 4 + r;
                const int c = c0 + nj * 16 + lr;
                const int b = p / HW, hw = p % HW;
                const size_t idx = ((size_t)b * C + c) * HW + hw;
                Outp[idx] = __bfloat162float(X1[idx]) + acc[mi][nj][r];
            }
}

extern "C" void kernel_launch(void* const* d_in, const int* in_sizes, int n_in,
                              void* d_out, int out_size, void* d_ws, size_t ws_size,
                              hipStream_t stream) {
    (void)in_sizes; (void)n_in; (void)out_size; (void)ws_size;
    const float* x     = (const float*)d_in[0];
    const float* mask  = (const float*)d_in[1];
    const float* edge  = (const float*)d_in[2];
    const float* ln1w  = (const float*)d_in[3];
    const float* ln1b  = (const float*)d_in[4];
    const float* Wq    = (const float*)d_in[5];
    const float* Wk    = (const float*)d_in[6];
    const float* Wv    = (const float*)d_in[7];
    const float* ln2w  = (const float*)d_in[8];
    const float* ln2b  = (const float*)d_in[9];
    const float* w_in  = (const float*)d_in[10];
    const float* w_dw  = (const float*)d_in[11];
    const float* w_out = (const float*)d_in[12];
    float* out = (float*)d_out;

    char* ws = (char*)d_ws;
    // persistent: [0, 7.93M) x1 bf16 ; [7.93M, 15.86M) xn2 bf16 ;
    // [15.86M, 47.58M) u_half bf16 ; [47.58M, 79.30M) g bf16. Total = 79,298,560 B.
    __hip_bfloat16* x1  = (__hip_bfloat16*)(ws + 0);
    __hip_bfloat16* xn2 = (__hip_bfloat16*)(ws + 7929856);
    __hip_bfloat16* uh  = (__hip_bfloat16*)(ws + 15859712);
    __hip_bfloat16* g   = (__hip_bfloat16*)(ws + 47579136);
    // transient (dead before u_half/g are written):
    __hip_bfloat16* qb  = (__hip_bfloat16*)(ws + 15859712);
    __hip_bfloat16* kb  = (__hip_bfloat16*)(ws + 23789568);
    __hip_bfloat16* vb  = (__hip_bfloat16*)(ws + 31719424);
    __hip_bfloat16* eb  = (__hip_bfloat16*)(ws + 39649280);
    __hip_bfloat16* xnm = (__hip_bfloat16*)(ws + 47579136);

    k_pre<<<968, 256, 0, stream>>>(x, mask, edge, ln1w, ln1b, xnm, eb);
    k_gemmQKV<<<dim3(121, 3), 512, 0, stream>>>(eb, xnm, Wq, Wk, Wv, qb, kb, vb);
    k_attn2<<<968, 256, 0, stream>>>(qb, kb, vb, x, x1);
    k_ln2<<<968, 256, 0, stream>>>(x1, ln2w, ln2b, xn2);
    k_gemm128<<<dim3(121, 4), 512, 0, stream>>>(xn2, w_in, uh, 512, 0);
    k_dw<<<3872, 256, 0, stream>>>(uh, w_dw, g, 0);
    k_gemm128<<<dim3(121, 4), 512, 0, stream>>>(xn2, w_in, uh, 512, 1);
    k_dw<<<3872, 256, 0, stream>>>(uh, w_dw, g, 1);
    k_gemm512<<<dim3(121, 2), 512, 0, stream>>>(g, w_out, x1, out);
}